// Round 1
// baseline (7792.228 us; speedup 1.0000x reference)
//
#include <hip/hip_runtime.h>

typedef _Float16 half8 __attribute__((ext_vector_type(8)));
typedef float floatx4 __attribute__((ext_vector_type(4)));

#define T_STEPS 512
#define BATCH 64
#define IN_DIM 256
#define HID 512
#define NBLK_TOT 128u

__device__ inline float sig_f(float x) { return 1.f / (1.f + __expf(-x)); }
__device__ inline float tanh_f(float x) {
  float t = __expf(-2.f * fabsf(x));
  float r = (1.f - t) / (1.f + t);
  return copysignf(r, x);
}

// Convert x to fp16, seed h buffers from hidden_cell, zero the barrier counter.
__global__ void init_kernel(const float* __restrict__ x, const float* __restrict__ hc,
                            _Float16* __restrict__ x16, _Float16* __restrict__ h0b,
                            _Float16* __restrict__ h1b, unsigned* __restrict__ bar) {
  size_t i = (size_t)blockIdx.x * blockDim.x + threadIdx.x;
  size_t stride = (size_t)gridDim.x * blockDim.x;
  const size_t n = (size_t)T_STEPS * BATCH * IN_DIM;
  for (size_t idx = i; idx < n; idx += stride) x16[idx] = (_Float16)x[idx];
  if (i < 32768) {
    // h[-1] lives at parity 1 of each double buffer
    h0b[32768 + i] = (_Float16)hc[i];          // hidden_cell[0][0]
    h1b[32768 + i] = (_Float16)hc[32768 + i];  // hidden_cell[0][1]
  }
  if (i == 0) *bar = 0u;
}

// Persistent 2-layer LSTM. Blocks 0..63: layer 0 (8 h-cols each).
// Blocks 64..127: layer 1. One device barrier per pipelined timestep.
__global__ __launch_bounds__(256) void lstm_kernel(
    const _Float16* __restrict__ x16, _Float16* __restrict__ h0b, _Float16* __restrict__ h1b,
    unsigned* __restrict__ bar,
    const float* __restrict__ W_ih0, const float* __restrict__ W_hh0,
    const float* __restrict__ b_ih0, const float* __restrict__ b_hh0,
    const float* __restrict__ W_ih1, const float* __restrict__ W_hh1,
    const float* __restrict__ b_ih1, const float* __restrict__ b_hh1,
    const float* __restrict__ W_out, const float* __restrict__ b_out,
    const float* __restrict__ hc, float* __restrict__ out) {
  __shared__ __align__(16) _Float16 wlds[32 * 1032];  // weight slice, fp16, padded pitch
  __shared__ float cbuf[64 * 36];                     // gate preacts [batch][32 rows]
  __shared__ float cstate[512];                       // c state [batch][8 cols]
  __shared__ float blds[32];                          // combined bias

  const int bq = blockIdx.x;
  const bool isL0 = bq < 64;
  const int q = isL0 ? bq : bq - 64;
  const int col0 = q * 8;
  const int Ka = isL0 ? 256 : 512;   // K of input-side matmul
  const int K = Ka + 512;            // + recurrent K
  const int WP = K + 8;              // padded LDS pitch (breaks bank aliasing)
  const float* Wa = isL0 ? W_ih0 : W_ih1;
  const float* Wb = isL0 ? W_hh0 : W_hh1;
  const float* bia = isL0 ? b_ih0 : b_ih1;
  const float* bib = isL0 ? b_hh0 : b_hh1;

  // Stage this block's 32 gate rows (4 gates x 8 cols), fp32 -> fp16 LDS.
  for (int idx = threadIdx.x; idx < 32 * K; idx += 256) {
    int r = idx / K;
    int k = idx - r * K;
    int g = r >> 3, j = r & 7;
    int grow = g * HID + col0 + j;  // PyTorch gate order i,f,g,o
    float w = (k < Ka) ? Wa[(size_t)grow * Ka + k] : Wb[(size_t)grow * HID + (k - Ka)];
    wlds[r * WP + k] = (_Float16)w;
  }
  if (threadIdx.x < 32) {
    int g = threadIdx.x >> 3, j = threadIdx.x & 7;
    int grow = g * HID + col0 + j;
    blds[threadIdx.x] = bia[grow] + bib[grow];
  }
  {
    int layer = isL0 ? 0 : 1;
    for (int idx = threadIdx.x; idx < 512; idx += 256) {
      int m = idx >> 3, j = idx & 7;
      cstate[idx] = hc[(size_t)(2 + layer) * 32768 + m * HID + col0 + j];  // hidden_cell[1][layer]
    }
  }
  __syncthreads();

  const int lane = threadIdx.x & 63;
  const int wv = threadIdx.x >> 6;
  const int lrow = lane & 15;        // A: m, B: n  (16x16x32 f16 layout)
  const int kq = (lane >> 4) * 8;    // k offset within 32-chunk
  const int m0 = wv * 16;            // wave's batch tile
  const _Float16* wrow0 = wlds + lrow * WP;
  const _Float16* wrow1 = wlds + (16 + lrow) * WP;

  unsigned epoch = 0;
  for (int it = 0; it <= T_STEPS; ++it) {
    const bool active = isL0 ? (it < T_STEPS) : (it >= 1);
    if (active) {
      const int t = isL0 ? it : it - 1;
      const _Float16* A0;
      int p0, nk0;
      const _Float16* A1;
      _Float16* dst;
      if (isL0) {
        A0 = x16 + (size_t)t * (BATCH * IN_DIM); p0 = IN_DIM; nk0 = 8;
        A1 = h0b + ((t - 1) & 1) * 32768;   // h0[t-1]
        dst = h0b + (t & 1) * 32768;        // h0[t]
      } else {
        A0 = h0b + (t & 1) * 32768; p0 = HID; nk0 = 16;  // h0[t] (made last iter)
        A1 = h1b + ((t - 1) & 1) * 32768;   // h1[t-1]
        dst = h1b + (t & 1) * 32768;        // h1[t]
      }
      floatx4 acc0 = {0.f, 0.f, 0.f, 0.f};
      floatx4 acc1 = {0.f, 0.f, 0.f, 0.f};
      const _Float16* a0p = A0 + (m0 + lrow) * p0 + kq;
      const _Float16* a1p = A1 + (m0 + lrow) * HID + kq;
      #pragma unroll 4
      for (int c = 0; c < nk0; ++c) {
        half8 a = *(const half8*)(a0p + c * 32);
        half8 b0v = *(const half8*)(wrow0 + c * 32 + kq);
        half8 b1v = *(const half8*)(wrow1 + c * 32 + kq);
        acc0 = __builtin_amdgcn_mfma_f32_16x16x32_f16(a, b0v, acc0, 0, 0, 0);
        acc1 = __builtin_amdgcn_mfma_f32_16x16x32_f16(a, b1v, acc1, 0, 0, 0);
      }
      const int kOff = nk0 * 32;
      #pragma unroll 4
      for (int c = 0; c < 16; ++c) {
        half8 a = *(const half8*)(a1p + c * 32);
        half8 b0v = *(const half8*)(wrow0 + kOff + c * 32 + kq);
        half8 b1v = *(const half8*)(wrow1 + kOff + c * 32 + kq);
        acc0 = __builtin_amdgcn_mfma_f32_16x16x32_f16(a, b0v, acc0, 0, 0, 0);
        acc1 = __builtin_amdgcn_mfma_f32_16x16x32_f16(a, b1v, acc1, 0, 0, 0);
      }
      // C/D layout: col = lane&15 (gate row), row = (lane>>4)*4 + reg (batch)
      const int mrow = m0 + (lane >> 4) * 4;
      #pragma unroll
      for (int r2 = 0; r2 < 4; ++r2) {
        cbuf[(mrow + r2) * 36 + lrow] = acc0[r2];
        cbuf[(mrow + r2) * 36 + 16 + lrow] = acc1[r2];
      }
      __syncthreads();
      // gates + state update for 64 batches x 8 cols
      for (int p = threadIdx.x; p < 512; p += 256) {
        int j = p & 7, m = p >> 3;
        float xi = cbuf[m * 36 + j] + blds[j];
        float xf = cbuf[m * 36 + 8 + j] + blds[8 + j];
        float xg = cbuf[m * 36 + 16 + j] + blds[16 + j];
        float xo = cbuf[m * 36 + 24 + j] + blds[24 + j];
        float ig = sig_f(xi), fg = sig_f(xf), gg = tanh_f(xg), og = sig_f(xo);
        float c = fg * cstate[p] + ig * gg;
        cstate[p] = c;
        float h = og * tanh_f(c);
        dst[m * HID + col0 + j] = (_Float16)h;
      }
    }
    // device-wide barrier (release h, arrive, spin, acquire)
    epoch++;
    __syncthreads();
    if (threadIdx.x == 0) {
      __threadfence();
      atomicAdd(bar, 1u);
      while (__hip_atomic_load(bar, __ATOMIC_RELAXED, __HIP_MEMORY_SCOPE_AGENT) < NBLK_TOT * epoch)
        __builtin_amdgcn_s_sleep(4);
      __threadfence();
    }
    __syncthreads();
  }

  // Final linear: out[64,256] = h1[511] @ W_out^T + b_out. Blocks 0..63, 4 out cols each.
  if (isL0) {
    const int ocl = threadIdx.x & 3;
    const int m = threadIdx.x >> 2;
    const int oc = q * 4 + ocl;
    const _Float16* hrow = h1b + 32768 + m * HID;  // h1[511] at parity 1
    const float* wrow = W_out + (size_t)oc * HID;
    float sum = 0.f;
    #pragma unroll 4
    for (int h = 0; h < HID; h += 8) {
      half8 hv = *(const half8*)(hrow + h);
      #pragma unroll
      for (int e = 0; e < 8; ++e) sum += (float)hv[e] * wrow[h + e];
    }
    out[m * 256 + oc] = sum + b_out[oc];
  }
}

extern "C" void kernel_launch(void* const* d_in, const int* in_sizes, int n_in,
                              void* d_out, int out_size, void* d_ws, size_t ws_size,
                              hipStream_t stream) {
  const float* x     = (const float*)d_in[0];
  const float* hc    = (const float*)d_in[1];
  const float* W_ih0 = (const float*)d_in[2];
  const float* W_hh0 = (const float*)d_in[3];
  const float* b_ih0 = (const float*)d_in[4];
  const float* b_hh0 = (const float*)d_in[5];
  const float* W_ih1 = (const float*)d_in[6];
  const float* W_hh1 = (const float*)d_in[7];
  const float* b_ih1 = (const float*)d_in[8];
  const float* b_hh1 = (const float*)d_in[9];
  const float* W_out = (const float*)d_in[10];
  const float* b_out = (const float*)d_in[11];
  float* out = (float*)d_out;

  char* ws = (char*)d_ws;
  _Float16* x16 = (_Float16*)ws;                         // 16,777,216 B
  _Float16* h0b = (_Float16*)(ws + 16777216);            // 131,072 B (2 x 64 x 512)
  _Float16* h1b = (_Float16*)(ws + 16777216 + 131072);   // 131,072 B
  unsigned* bar = (unsigned*)(ws + 16777216 + 262144);   // 4 B

  init_kernel<<<2048, 256, 0, stream>>>(x, hc, x16, h0b, h1b, bar);
  lstm_kernel<<<128, 256, 0, stream>>>(x16, h0b, h1b, bar,
                                       W_ih0, W_hh0, b_ih0, b_hh0,
                                       W_ih1, W_hh1, b_ih1, b_hh1,
                                       W_out, b_out, hc, out);
}

// Round 2
// 4772.932 us; speedup vs baseline: 1.6326x; 1.6326x over previous
//
#include <hip/hip_runtime.h>

typedef _Float16 half8 __attribute__((ext_vector_type(8)));
typedef float floatx4 __attribute__((ext_vector_type(4)));
typedef unsigned long long u64;

#define T_STEPS 512
#define IN_DIM 256
#define HID 512
#define RING 8

__device__ inline float sig_f(float x) { return 1.f / (1.f + __expf(-x)); }
__device__ inline float tanh_f(float x) {
  float t = __expf(-2.f * fabsf(x));
  return copysignf((1.f - t) / (1.f + t), x);
}

// Coherent (agent-scope, cache-bypassing) accessors for cross-block data.
// Relaxed atomics emit sc0/sc1 memops WITHOUT buffer_wbl2/buffer_inv sweeps.
__device__ inline u64 cload64(const _Float16* p) {
  return __hip_atomic_load((const u64*)p, __ATOMIC_RELAXED, __HIP_MEMORY_SCOPE_AGENT);
}
__device__ inline half8 cload_h8(const _Float16* p) {
  union { u64 u[2]; half8 v; } r;
  r.u[0] = cload64(p);
  r.u[1] = cload64(p + 4);
  return r.v;
}
__device__ inline void cstore_pair(_Float16* p, float a, float b) {
  union { unsigned u; _Float16 h[2]; } pk;
  pk.h[0] = (_Float16)a; pk.h[1] = (_Float16)b;
  __hip_atomic_store((unsigned*)p, pk.u, __ATOMIC_RELAXED, __HIP_MEMORY_SCOPE_AGENT);
}
__device__ inline unsigned cload_bar(const unsigned* p) {
  return __hip_atomic_load(p, __ATOMIC_RELAXED, __HIP_MEMORY_SCOPE_AGENT);
}

__global__ void init_kernel(const float* __restrict__ x, const float* __restrict__ hc,
                            _Float16* __restrict__ x16, _Float16* __restrict__ h0b,
                            _Float16* __restrict__ h1b, unsigned* __restrict__ bars) {
  size_t i = (size_t)blockIdx.x * blockDim.x + threadIdx.x;
  size_t stride = (size_t)gridDim.x * blockDim.x;
  const size_t n = (size_t)T_STEPS * 64 * IN_DIM;
  for (size_t idx = i; idx < n; idx += stride) x16[idx] = (_Float16)x[idx];
  if (i < 16384) {
    // h0[-1] -> ring slot 7; h1[-1] -> parity 1. Coherent stores (consumers bypass L2).
    cstore_pair(h0b + (size_t)(RING - 1) * 32768 + 2 * i, hc[2 * i], hc[2 * i + 1]);
    cstore_pair(h1b + 32768 + 2 * i, hc[32768 + 2 * i], hc[32768 + 2 * i + 1]);
  }
  if (i == 0) {
    __hip_atomic_store(&bars[0], 0u, __ATOMIC_RELAXED, __HIP_MEMORY_SCOPE_AGENT);
    __hip_atomic_store(&bars[32], 0u, __ATOMIC_RELAXED, __HIP_MEMORY_SCOPE_AGENT);
  }
}

// Blocks 0..63: layer 0 (8 h-cols each). Blocks 64..127: layer 1.
// Per-layer 64-wide barriers (bar0/bar1), one-way L0->L1 dep, 8-deep h0 ring.
// NO __threadfence anywhere: all cross-block data moves via sc0/sc1 atomics;
// release ordering = s_waitcnt vmcnt(0) + __syncthreads before the arrive-add.
__global__ __launch_bounds__(256) void lstm_kernel(
    const _Float16* __restrict__ x16, _Float16* __restrict__ h0b, _Float16* __restrict__ h1b,
    unsigned* __restrict__ bars,
    const float* __restrict__ W_ih0, const float* __restrict__ W_hh0,
    const float* __restrict__ b_ih0, const float* __restrict__ b_hh0,
    const float* __restrict__ W_ih1, const float* __restrict__ W_hh1,
    const float* __restrict__ b_ih1, const float* __restrict__ b_hh1,
    const float* __restrict__ W_out, const float* __restrict__ b_out,
    const float* __restrict__ hc, float* __restrict__ out) {
  __shared__ __align__(16) _Float16 wlds[32 * 1032];
  __shared__ float cbuf[64 * 36];
  __shared__ float cstate[512];
  __shared__ float blds[32];

  unsigned* bar0 = &bars[0];
  unsigned* bar1 = &bars[32];

  const int bq = blockIdx.x;
  const bool isL0 = bq < 64;
  const int q = isL0 ? bq : bq - 64;
  const int col0 = q * 8;
  const int Ka = isL0 ? IN_DIM : HID;
  const int K = Ka + HID;
  const int WP = K + 8;
  const float* Wa = isL0 ? W_ih0 : W_ih1;
  const float* Wb = isL0 ? W_hh0 : W_hh1;
  const float* bia = isL0 ? b_ih0 : b_ih1;
  const float* bib = isL0 ? b_hh0 : b_hh1;

  for (int idx = threadIdx.x; idx < 32 * K; idx += 256) {
    int r = idx / K;
    int k = idx - r * K;
    int g = r >> 3, j = r & 7;
    int grow = g * HID + col0 + j;
    float w = (k < Ka) ? Wa[(size_t)grow * Ka + k] : Wb[(size_t)grow * HID + (k - Ka)];
    wlds[r * WP + k] = (_Float16)w;
  }
  if (threadIdx.x < 32) {
    int g = threadIdx.x >> 3, j = threadIdx.x & 7;
    int grow = g * HID + col0 + j;
    blds[threadIdx.x] = bia[grow] + bib[grow];
  }
  {
    int layer = isL0 ? 0 : 1;
    for (int idx = threadIdx.x; idx < 512; idx += 256) {
      int m = idx >> 3, j = idx & 7;
      cstate[idx] = hc[(size_t)(2 + layer) * 32768 + m * HID + col0 + j];
    }
  }
  __syncthreads();

  const int lane = threadIdx.x & 63;
  const int wv = threadIdx.x >> 6;
  const int lrow = lane & 15;
  const int kq = (lane >> 4) * 8;
  const int m0 = wv * 16;
  const _Float16* wrow0 = wlds + lrow * WP;
  const _Float16* wrow1 = wlds + (16 + lrow) * WP;

  // Recurrent-half B fragments live in registers (kills 32 LDS b128 reads/step).
  half8 breg0[16], breg1[16];
#pragma unroll
  for (int c = 0; c < 16; ++c) {
    breg0[c] = *(const half8*)(wrow0 + Ka + c * 32 + kq);
    breg1[c] = *(const half8*)(wrow1 + Ka + c * 32 + kq);
  }

  const int gm = threadIdx.x >> 2;            // gate-phase batch row
  const int gj = (threadIdx.x & 3) * 2;       // gate-phase col pair

  for (int t = 0; t < T_STEPS; ++t) {
    floatx4 acc0 = {0.f, 0.f, 0.f, 0.f};
    floatx4 acc1 = {0.f, 0.f, 0.f, 0.f};
    _Float16* dst;

    if (isL0) {
      // X phase: no cross-block dependency — compute before the wait.
      const _Float16* a0p = x16 + (size_t)t * (64 * IN_DIM) + (m0 + lrow) * IN_DIM + kq;
#pragma unroll
      for (int c = 0; c < 8; ++c) {
        half8 a = *(const half8*)(a0p + c * 32);
        half8 b0v = *(const half8*)(wrow0 + c * 32 + kq);
        half8 b1v = *(const half8*)(wrow1 + c * 32 + kq);
        acc0 = __builtin_amdgcn_mfma_f32_16x16x32_f16(a, b0v, acc0, 0, 0, 0);
        acc1 = __builtin_amdgcn_mfma_f32_16x16x32_f16(a, b1v, acc1, 0, 0, 0);
      }
      if (threadIdx.x == 0) {
        if (t > 0) { unsigned tg = 64u * t; while (cload_bar(bar0) < tg) {} }
        if (t >= RING) { unsigned tg = 64u * (t - RING + 1); while (cload_bar(bar1) < tg) {} }
      }
      __syncthreads();
      asm volatile("" ::: "memory");
      const _Float16* a1p = h0b + (size_t)((t - 1) & (RING - 1)) * 32768 + (m0 + lrow) * HID + kq;
#pragma unroll
      for (int c = 0; c < 16; ++c) {
        half8 a = cload_h8(a1p + c * 32);
        acc0 = __builtin_amdgcn_mfma_f32_16x16x32_f16(a, breg0[c], acc0, 0, 0, 0);
        acc1 = __builtin_amdgcn_mfma_f32_16x16x32_f16(a, breg1[c], acc1, 0, 0, 0);
      }
      dst = h0b + (size_t)(t & (RING - 1)) * 32768;
    } else {
      if (threadIdx.x == 0) {
        unsigned tg = 64u * (t + 1);  // h0[t] ready
        while (cload_bar(bar0) < tg) {}
      }
      __syncthreads();
      asm volatile("" ::: "memory");
      const _Float16* a0p = h0b + (size_t)(t & (RING - 1)) * 32768 + (m0 + lrow) * HID + kq;
#pragma unroll
      for (int c = 0; c < 16; ++c) {
        half8 a = cload_h8(a0p + c * 32);
        half8 b0v = *(const half8*)(wrow0 + c * 32 + kq);
        half8 b1v = *(const half8*)(wrow1 + c * 32 + kq);
        acc0 = __builtin_amdgcn_mfma_f32_16x16x32_f16(a, b0v, acc0, 0, 0, 0);
        acc1 = __builtin_amdgcn_mfma_f32_16x16x32_f16(a, b1v, acc1, 0, 0, 0);
      }
      if (threadIdx.x == 0 && t > 0) {
        unsigned tg = 64u * t;  // peer h1[t-1] ready
        while (cload_bar(bar1) < tg) {}
      }
      __syncthreads();
      asm volatile("" ::: "memory");
      const _Float16* a1p = h1b + (size_t)((t - 1) & 1) * 32768 + (m0 + lrow) * HID + kq;
#pragma unroll
      for (int c = 0; c < 16; ++c) {
        half8 a = cload_h8(a1p + c * 32);
        acc0 = __builtin_amdgcn_mfma_f32_16x16x32_f16(a, breg0[c], acc0, 0, 0, 0);
        acc1 = __builtin_amdgcn_mfma_f32_16x16x32_f16(a, breg1[c], acc1, 0, 0, 0);
      }
      dst = h1b + (size_t)(t & 1) * 32768;
    }

    // C/D layout: col = lane&15 (gate row), row = (lane>>4)*4 + reg (batch)
    const int mrow = m0 + (lane >> 4) * 4;
#pragma unroll
    for (int r2 = 0; r2 < 4; ++r2) {
      cbuf[(mrow + r2) * 36 + lrow] = acc0[r2];
      cbuf[(mrow + r2) * 36 + 16 + lrow] = acc1[r2];
    }
    __syncthreads();

    float hv[2];
#pragma unroll
    for (int e = 0; e < 2; ++e) {
      int j = gj + e;
      float xi = cbuf[gm * 36 + j] + blds[j];
      float xf = cbuf[gm * 36 + 8 + j] + blds[8 + j];
      float xg = cbuf[gm * 36 + 16 + j] + blds[16 + j];
      float xo = cbuf[gm * 36 + 24 + j] + blds[24 + j];
      float ig = sig_f(xi), fg = sig_f(xf), gg = tanh_f(xg), og = sig_f(xo);
      float c = fg * cstate[gm * 8 + j] + ig * gg;
      cstate[gm * 8 + j] = c;
      hv[e] = og * tanh_f(c);
    }
    cstore_pair(dst + gm * HID + col0 + gj, hv[0], hv[1]);

    // arrive: drain write-through stores, join block, single relaxed RMW.
    asm volatile("s_waitcnt vmcnt(0)" ::: "memory");
    __syncthreads();
    if (threadIdx.x == 0) {
      __hip_atomic_fetch_add(isL0 ? bar0 : bar1, 1u, __ATOMIC_RELAXED, __HIP_MEMORY_SCOPE_AGENT);
    }
    asm volatile("" ::: "memory");
  }

  // Final linear on L0 blocks: out[64,256] = h1[511] @ W_out^T + b_out.
  if (isL0) {
    if (threadIdx.x == 0) {
      unsigned tg = 64u * T_STEPS;
      while (cload_bar(bar1) < tg) {}
    }
    __syncthreads();
    asm volatile("" ::: "memory");
    const int oc = q * 4 + (threadIdx.x & 3);
    const int m = threadIdx.x >> 2;
    const _Float16* hrow = h1b + 32768 + m * HID;  // h1[511] at parity 1
    const float* wrow = W_out + (size_t)oc * HID;
    float sum = 0.f;
#pragma unroll 4
    for (int h = 0; h < HID; h += 8) {
      half8 hvv = cload_h8(hrow + h);
#pragma unroll
      for (int e = 0; e < 8; ++e) sum += (float)hvv[e] * wrow[h + e];
    }
    out[m * 256 + oc] = sum + b_out[oc];
  }
}

extern "C" void kernel_launch(void* const* d_in, const int* in_sizes, int n_in,
                              void* d_out, int out_size, void* d_ws, size_t ws_size,
                              hipStream_t stream) {
  const float* x     = (const float*)d_in[0];
  const float* hc    = (const float*)d_in[1];
  const float* W_ih0 = (const float*)d_in[2];
  const float* W_hh0 = (const float*)d_in[3];
  const float* b_ih0 = (const float*)d_in[4];
  const float* b_hh0 = (const float*)d_in[5];
  const float* W_ih1 = (const float*)d_in[6];
  const float* W_hh1 = (const float*)d_in[7];
  const float* b_ih1 = (const float*)d_in[8];
  const float* b_hh1 = (const float*)d_in[9];
  const float* W_out = (const float*)d_in[10];
  const float* b_out = (const float*)d_in[11];
  float* out = (float*)d_out;

  char* ws = (char*)d_ws;
  _Float16* x16 = (_Float16*)ws;                              // 16 MB
  _Float16* h0b = (_Float16*)(ws + 16777216);                 // 8 x 64 KB ring
  _Float16* h1b = (_Float16*)(ws + 16777216 + 8 * 65536);     // 2 x 64 KB
  unsigned* bars = (unsigned*)(ws + 16777216 + 10 * 65536);   // bar0 @0, bar1 @128B

  init_kernel<<<2048, 256, 0, stream>>>(x, hc, x16, h0b, h1b, bars);
  lstm_kernel<<<128, 256, 0, stream>>>(x16, h0b, h1b, bars,
                                       W_ih0, W_hh0, b_ih0, b_hh0,
                                       W_ih1, W_hh1, b_ih1, b_hh1,
                                       W_out, b_out, hc, out);
}

// Round 3
// 4715.369 us; speedup vs baseline: 1.6525x; 1.0122x over previous
//
#include <hip/hip_runtime.h>

typedef _Float16 half8 __attribute__((ext_vector_type(8)));
typedef float floatx4 __attribute__((ext_vector_type(4)));
typedef unsigned long long u64;

#define T_STEPS 512
#define IN_DIM 256
#define HID 512
#define RING 8
#define FLAG_STRIDE 32  // uints -> 128 B per flag line

__device__ inline float sig_f(float x) { return 1.f / (1.f + __expf(-x)); }
__device__ inline float tanh_f(float x) {
  float t = __expf(-2.f * fabsf(x));
  return copysignf((1.f - t) / (1.f + t), x);
}

// Coherent (agent-scope, cache-bypassing) accessors for cross-block data.
__device__ inline u64 cload64(const _Float16* p) {
  return __hip_atomic_load((const u64*)p, __ATOMIC_RELAXED, __HIP_MEMORY_SCOPE_AGENT);
}
__device__ inline half8 cload_h8(const _Float16* p) {
  union { u64 u[2]; half8 v; } r;
  r.u[0] = cload64(p);
  r.u[1] = cload64(p + 4);
  return r.v;
}
__device__ inline void cstore_pair(_Float16* p, float a, float b) {
  union { unsigned u; _Float16 h[2]; } pk;
  pk.h[0] = (_Float16)a; pk.h[1] = (_Float16)b;
  __hip_atomic_store((unsigned*)p, pk.u, __ATOMIC_RELAXED, __HIP_MEMORY_SCOPE_AGENT);
}

// Wave-parallel flag barrier: lane i polls block i's flag; no RMW anywhere.
// Must be called by a full wave (threads 0..63) while other waves sit at a barrier.
__device__ inline void wait_flags64(const unsigned* flags, unsigned target) {
  const unsigned* p = flags + (threadIdx.x & 63) * FLAG_STRIDE;
  while (true) {
    unsigned v = __hip_atomic_load(p, __ATOMIC_RELAXED, __HIP_MEMORY_SCOPE_AGENT);
    if (__all((int)(v >= target))) return;
    __builtin_amdgcn_s_sleep(1);
  }
}

__global__ void init_kernel(const float* __restrict__ x, const float* __restrict__ hc,
                            _Float16* __restrict__ x16, _Float16* __restrict__ h0b,
                            _Float16* __restrict__ h1b, unsigned* __restrict__ flags0,
                            unsigned* __restrict__ flags1) {
  size_t i = (size_t)blockIdx.x * blockDim.x + threadIdx.x;
  size_t stride = (size_t)gridDim.x * blockDim.x;
  const size_t n = (size_t)T_STEPS * 64 * IN_DIM;
  for (size_t idx = i; idx < n; idx += stride) x16[idx] = (_Float16)x[idx];
  if (i < 16384) {
    // h0[-1] -> ring slot 7; h1[-1] -> parity 1 (coherent stores).
    cstore_pair(h0b + (size_t)(RING - 1) * 32768 + 2 * i, hc[2 * i], hc[2 * i + 1]);
    cstore_pair(h1b + 32768 + 2 * i, hc[32768 + 2 * i], hc[32768 + 2 * i + 1]);
  }
  if (i < 64) {
    __hip_atomic_store(flags0 + i * FLAG_STRIDE, 0u, __ATOMIC_RELAXED, __HIP_MEMORY_SCOPE_AGENT);
    __hip_atomic_store(flags1 + i * FLAG_STRIDE, 0u, __ATOMIC_RELAXED, __HIP_MEMORY_SCOPE_AGENT);
  }
}

// Blocks 0..63: layer 0 (8 h-cols each). Blocks 64..127: layer 1.
// Per-layer flag-array barriers (parallel arrive stores, wave-parallel poll),
// one-way L0->L1 dep, 8-deep h0 ring. No fences, no atomic RMW.
__global__ __launch_bounds__(256) void lstm_kernel(
    const _Float16* __restrict__ x16, _Float16* __restrict__ h0b, _Float16* __restrict__ h1b,
    unsigned* __restrict__ flags0, unsigned* __restrict__ flags1,
    const float* __restrict__ W_ih0, const float* __restrict__ W_hh0,
    const float* __restrict__ b_ih0, const float* __restrict__ b_hh0,
    const float* __restrict__ W_ih1, const float* __restrict__ W_hh1,
    const float* __restrict__ b_ih1, const float* __restrict__ b_hh1,
    const float* __restrict__ W_out, const float* __restrict__ b_out,
    const float* __restrict__ hc, float* __restrict__ out) {
  __shared__ __align__(16) _Float16 wlds[32 * 1032];
  __shared__ float cbuf[64 * 36];
  __shared__ float cstate[512];
  __shared__ float blds[32];

  const int bq = blockIdx.x;
  const bool isL0 = bq < 64;
  const int q = isL0 ? bq : bq - 64;
  const int col0 = q * 8;
  const int Ka = isL0 ? IN_DIM : HID;
  const int K = Ka + HID;
  const int WP = K + 8;
  const float* Wa = isL0 ? W_ih0 : W_ih1;
  const float* Wb = isL0 ? W_hh0 : W_hh1;
  const float* bia = isL0 ? b_ih0 : b_ih1;
  const float* bib = isL0 ? b_hh0 : b_hh1;
  unsigned* myflag = (isL0 ? flags0 : flags1) + q * FLAG_STRIDE;

  for (int idx = threadIdx.x; idx < 32 * K; idx += 256) {
    int r = idx / K;
    int k = idx - r * K;
    int g = r >> 3, j = r & 7;
    int grow = g * HID + col0 + j;  // PyTorch gate order i,f,g,o
    float w = (k < Ka) ? Wa[(size_t)grow * Ka + k] : Wb[(size_t)grow * HID + (k - Ka)];
    wlds[r * WP + k] = (_Float16)w;
  }
  if (threadIdx.x < 32) {
    int g = threadIdx.x >> 3, j = threadIdx.x & 7;
    int grow = g * HID + col0 + j;
    blds[threadIdx.x] = bia[grow] + bib[grow];
  }
  {
    int layer = isL0 ? 0 : 1;
    for (int idx = threadIdx.x; idx < 512; idx += 256) {
      int m = idx >> 3, j = idx & 7;
      cstate[idx] = hc[(size_t)(2 + layer) * 32768 + m * HID + col0 + j];
    }
  }
  __syncthreads();

  const int lane = threadIdx.x & 63;
  const int wv = threadIdx.x >> 6;
  const int lrow = lane & 15;
  const int kq = (lane >> 4) * 8;
  const int m0 = wv * 16;
  const _Float16* wrow0 = wlds + lrow * WP;
  const _Float16* wrow1 = wlds + (16 + lrow) * WP;

  // Recurrent-half B fragments in registers.
  half8 breg0[16], breg1[16];
#pragma unroll
  for (int c = 0; c < 16; ++c) {
    breg0[c] = *(const half8*)(wrow0 + Ka + c * 32 + kq);
    breg1[c] = *(const half8*)(wrow1 + Ka + c * 32 + kq);
  }

  const int gm = threadIdx.x >> 2;
  const int gj = (threadIdx.x & 3) * 2;

  for (int t = 0; t < T_STEPS; ++t) {
    floatx4 acc0 = {0.f, 0.f, 0.f, 0.f};
    floatx4 acc1 = {0.f, 0.f, 0.f, 0.f};
    _Float16* dst;

    if (isL0) {
      // X phase: no cross-block dependency — compute before the wait.
      const _Float16* a0p = x16 + (size_t)t * (64 * IN_DIM) + (m0 + lrow) * IN_DIM + kq;
#pragma unroll
      for (int c = 0; c < 8; ++c) {
        half8 a = *(const half8*)(a0p + c * 32);
        half8 b0v = *(const half8*)(wrow0 + c * 32 + kq);
        half8 b1v = *(const half8*)(wrow1 + c * 32 + kq);
        acc0 = __builtin_amdgcn_mfma_f32_16x16x32_f16(a, b0v, acc0, 0, 0, 0);
        acc1 = __builtin_amdgcn_mfma_f32_16x16x32_f16(a, b1v, acc1, 0, 0, 0);
      }
      if (threadIdx.x < 64) {
        if (t > 0) wait_flags64(flags0, (unsigned)t);              // peers' h0[t-1] ready
        if (t >= RING) wait_flags64(flags1, (unsigned)(t - RING + 1));  // ring slot free
      }
      __syncthreads();
      asm volatile("" ::: "memory");
      const _Float16* a1p = h0b + (size_t)((t - 1) & (RING - 1)) * 32768 + (m0 + lrow) * HID + kq;
#pragma unroll
      for (int c = 0; c < 16; ++c) {
        half8 a = cload_h8(a1p + c * 32);
        acc0 = __builtin_amdgcn_mfma_f32_16x16x32_f16(a, breg0[c], acc0, 0, 0, 0);
        acc1 = __builtin_amdgcn_mfma_f32_16x16x32_f16(a, breg1[c], acc1, 0, 0, 0);
      }
      dst = h0b + (size_t)(t & (RING - 1)) * 32768;
    } else {
      if (threadIdx.x < 64) wait_flags64(flags0, (unsigned)(t + 1));  // h0[t] ready
      __syncthreads();
      asm volatile("" ::: "memory");
      const _Float16* a0p = h0b + (size_t)(t & (RING - 1)) * 32768 + (m0 + lrow) * HID + kq;
#pragma unroll
      for (int c = 0; c < 16; ++c) {
        half8 a = cload_h8(a0p + c * 32);
        half8 b0v = *(const half8*)(wrow0 + c * 32 + kq);
        half8 b1v = *(const half8*)(wrow1 + c * 32 + kq);
        acc0 = __builtin_amdgcn_mfma_f32_16x16x32_f16(a, b0v, acc0, 0, 0, 0);
        acc1 = __builtin_amdgcn_mfma_f32_16x16x32_f16(a, b1v, acc1, 0, 0, 0);
      }
      if (threadIdx.x < 64 && t > 0) wait_flags64(flags1, (unsigned)t);  // peer h1[t-1]
      __syncthreads();
      asm volatile("" ::: "memory");
      const _Float16* a1p = h1b + (size_t)((t - 1) & 1) * 32768 + (m0 + lrow) * HID + kq;
#pragma unroll
      for (int c = 0; c < 16; ++c) {
        half8 a = cload_h8(a1p + c * 32);
        acc0 = __builtin_amdgcn_mfma_f32_16x16x32_f16(a, breg0[c], acc0, 0, 0, 0);
        acc1 = __builtin_amdgcn_mfma_f32_16x16x32_f16(a, breg1[c], acc1, 0, 0, 0);
      }
      dst = h1b + (size_t)(t & 1) * 32768;
    }

    // C/D layout: col = lane&15 (gate row), row = (lane>>4)*4 + reg (batch)
    const int mrow = m0 + (lane >> 4) * 4;
#pragma unroll
    for (int r2 = 0; r2 < 4; ++r2) {
      cbuf[(mrow + r2) * 36 + lrow] = acc0[r2];
      cbuf[(mrow + r2) * 36 + 16 + lrow] = acc1[r2];
    }
    __syncthreads();

    float hv[2];
#pragma unroll
    for (int e = 0; e < 2; ++e) {
      int j = gj + e;
      float xi = cbuf[gm * 36 + j] + blds[j];
      float xf = cbuf[gm * 36 + 8 + j] + blds[8 + j];
      float xg = cbuf[gm * 36 + 16 + j] + blds[16 + j];
      float xo = cbuf[gm * 36 + 24 + j] + blds[24 + j];
      float ig = sig_f(xi), fg = sig_f(xf), gg = tanh_f(xg), og = sig_f(xo);
      float c = fg * cstate[gm * 8 + j] + ig * gg;
      cstate[gm * 8 + j] = c;
      hv[e] = og * tanh_f(c);
    }
    cstore_pair(dst + gm * HID + col0 + gj, hv[0], hv[1]);

    // Release: drain write-through stores, join block, one plain flag store.
    asm volatile("s_waitcnt vmcnt(0)" ::: "memory");
    __syncthreads();
    if (threadIdx.x == 0) {
      __hip_atomic_store(myflag, (unsigned)(t + 1), __ATOMIC_RELAXED, __HIP_MEMORY_SCOPE_AGENT);
    }
    asm volatile("" ::: "memory");
  }

  // Final linear on L0 blocks: out[64,256] = h1[511] @ W_out^T + b_out.
  if (isL0) {
    if (threadIdx.x < 64) wait_flags64(flags1, (unsigned)T_STEPS);
    __syncthreads();
    asm volatile("" ::: "memory");
    const int oc = q * 4 + (threadIdx.x & 3);
    const int m = threadIdx.x >> 2;
    const _Float16* hrow = h1b + 32768 + m * HID;  // h1[511] at parity 1
    const float* wrow = W_out + (size_t)oc * HID;
    float sum = 0.f;
#pragma unroll 4
    for (int h = 0; h < HID; h += 8) {
      half8 hvv = cload_h8(hrow + h);
#pragma unroll
      for (int e = 0; e < 8; ++e) sum += (float)hvv[e] * wrow[h + e];
    }
    out[m * 256 + oc] = sum + b_out[oc];
  }
}

extern "C" void kernel_launch(void* const* d_in, const int* in_sizes, int n_in,
                              void* d_out, int out_size, void* d_ws, size_t ws_size,
                              hipStream_t stream) {
  const float* x     = (const float*)d_in[0];
  const float* hc    = (const float*)d_in[1];
  const float* W_ih0 = (const float*)d_in[2];
  const float* W_hh0 = (const float*)d_in[3];
  const float* b_ih0 = (const float*)d_in[4];
  const float* b_hh0 = (const float*)d_in[5];
  const float* W_ih1 = (const float*)d_in[6];
  const float* W_hh1 = (const float*)d_in[7];
  const float* b_ih1 = (const float*)d_in[8];
  const float* b_hh1 = (const float*)d_in[9];
  const float* W_out = (const float*)d_in[10];
  const float* b_out = (const float*)d_in[11];
  float* out = (float*)d_out;

  char* ws = (char*)d_ws;
  _Float16* x16 = (_Float16*)ws;                              // 16 MB
  _Float16* h0b = (_Float16*)(ws + 16777216);                 // 8 x 64 KB ring
  _Float16* h1b = (_Float16*)(ws + 16777216 + 8 * 65536);     // 2 x 64 KB
  unsigned* flags0 = (unsigned*)(ws + 16777216 + 10 * 65536);            // 64 x 128 B
  unsigned* flags1 = (unsigned*)(ws + 16777216 + 10 * 65536 + 8192);     // 64 x 128 B

  init_kernel<<<2048, 256, 0, stream>>>(x, hc, x16, h0b, h1b, flags0, flags1);
  lstm_kernel<<<128, 256, 0, stream>>>(x16, h0b, h1b, flags0, flags1,
                                       W_ih0, W_hh0, b_ih0, b_hh0,
                                       W_ih1, W_hh1, b_ih1, b_hh1,
                                       W_out, b_out, hc, out);
}